// Round 13
// baseline (205.682 us; speedup 1.0000x reference)
//
#include <hip/hip_runtime.h>
#include <math.h>

#define B_    32
#define N_    784
#define D_    512
#define K_    10
#define RES_  28
#define INF_  100000.0f
#define TM    16
#define TILES (N_ / 16)   // 49
#define BIGF  3.0e38f
#define LDSW  788         // fallback kernel's padded dist row stride
#define BROW  520         // LDS B-tile row stride in shorts (1040 B)
#define NCH   34          // symmetric chunks per batch (<=13 tiles each)

typedef __attribute__((ext_vector_type(8))) short short8;
typedef __attribute__((ext_vector_type(4))) float f32x4;

// chunk tables: row-block i (64 rows), col-tile range [ts, te). Ordered by
// DESCENDING tile count so the HW block queue packs heavy chunks first.
__device__ __constant__ unsigned char CH_I[NCH] =
    {0,0,0,1,1,2,2,3,3,4,5,6, 7, 0,1,2,3,4,4,5,6,7,8,9, 1,10, 8, 5, 2,11, 9, 6, 3,12};
__device__ __constant__ unsigned char CH_TS[NCH] =
    {0,13,26,13,26,13,26,13,26,26,26,26, 28, 39,39,39,39,16,39,39,39,39,39,39, 4,40, 32, 20, 8,44, 36, 24, 12,48};
__device__ __constant__ unsigned char CH_TE[NCH] =
    {13,26,39,26,39,26,39,26,39,39,39,39, 39, 49,49,49,49,26,49,49,49,49,49,49, 13,49, 39, 26, 13,49, 39, 26, 13,49};

__device__ __forceinline__ unsigned short f2bf(float f) {
    unsigned u = __float_as_uint(f);
    unsigned r = (u + 0x7fffu + ((u >> 16) & 1u)) >> 16;   // RNE
    return (unsigned short)r;
}
__device__ __forceinline__ float bf2f(unsigned short h) {
    return __uint_as_float(((unsigned)h) << 16);
}

// async global->LDS, 16 B per lane: LDS dest = uniform base + lane*16.
__device__ __forceinline__ void gl_lds16(const void* g, void* l) {
    __builtin_amdgcn_global_load_lds(
        (const __attribute__((address_space(1))) unsigned int*)g,
        (__attribute__((address_space(3))) unsigned int*)(void*)l, 16, 0, 0);
}

// ---------------------------------------------------------------------------
// Kernel A: per-row inv_norm & sq, plus split-bf16 conversion
// x = hi + lo with hi=bf16(x), lo=bf16(x-hi). One wave per row.
// ---------------------------------------------------------------------------
__global__ __launch_bounds__(256) void norm_convert_kernel(
    const float* __restrict__ nf, float* __restrict__ inv_norm,
    float* __restrict__ sq, unsigned short* __restrict__ xhi,
    unsigned short* __restrict__ xlo)
{
    int wave = threadIdx.x >> 6;
    int lane = threadIdx.x & 63;
    int row  = blockIdx.x * 4 + wave;           // grid exactly covers B_*N_
    const float* rp = nf + (size_t)row * D_;
    float4 a = *(const float4*)(rp + lane * 8);
    float4 b = *(const float4*)(rp + lane * 8 + 4);
    float v[8] = {a.x, a.y, a.z, a.w, b.x, b.y, b.z, b.w};

    float s = 0.f;
    #pragma unroll
    for (int i = 0; i < 8; i++) s = fmaf(v[i], v[i], s);
    #pragma unroll
    for (int off = 32; off >= 1; off >>= 1)
        s += __shfl_xor(s, off, 64);
    if (lane == 0) {
        float nrm = sqrtf(s);
        float iv  = 1.0f / fmaxf(nrm, 1e-12f);
        inv_norm[row] = iv;
        sq[row]       = s * iv * iv;
    }

    unsigned short h[8], l[8];
    #pragma unroll
    for (int i = 0; i < 8; i++) {
        h[i] = f2bf(v[i]);
        float hf = bf2f(h[i]);
        l[i] = f2bf(v[i] - hf);
    }
    size_t off16 = (size_t)row * D_ + lane * 8;
    short8 h8, l8;
    #pragma unroll
    for (int i = 0; i < 8; i++) { h8[i] = (short)h[i]; l8[i] = (short)l[i]; }
    *(short8*)(xhi + off16) = h8;
    *(short8*)(xlo + off16) = l8;
}

// ---------------------------------------------------------------------------
// Kernel B: SYMMETRIC distance GEMM, 32-ROW blocks for occupancy. Round-12
// counters: all pipes <=25% at 2 blocks/CU -- barrier-serialization-bound.
// New shape: 4 waves = 2 pairs (16-row tiles) x 2 K-halves; each wave holds
// A for ONE tile, K-half only (64 VGPRs) -> ~130 total; single-buffer B tile
// (33.3 KB) + single PS (4 KB) = 37.4 KB LDS -> 4 blocks/CU (16 waves),
// cross-block overlap absorbs the two per-tile barrier drains.
// hf=0 wave stores direct rows; hf=1 stores the mirror float4 (t>=4i+4).
// ---------------------------------------------------------------------------
__global__ __launch_bounds__(256, 3) void gemm32(
    const unsigned short* __restrict__ xhi, const unsigned short* __restrict__ xlo,
    const float* __restrict__ rel, const float* __restrict__ inv_norm,
    const float* __restrict__ sqv, float* __restrict__ dist)
{
    __shared__ unsigned short Bs[2][16 * BROW];   // [hi/lo][tile] 33280 B
    __shared__ f32x4 PS[2][2][64];                // [pair][half][lane] 4096 B

    const int tid  = threadIdx.x;
    const int wv   = tid >> 6;
    const int lane = tid & 63;
    const int quad = lane >> 4;
    const int l16  = lane & 15;
    const int pr   = wv >> 1;           // pair: which 16-row tile of the 32
    const int hf   = wv & 1;            // K-half

    // 2176 blocks = 8 XCDs * (4 batches * 34 chunks * 2 half-blocks);
    // batch-major, heavy chunks first, both halves of a chunk adjacent.
    int gb   = blockIdx.x;
    int xcd  = gb & 7;
    int loc  = gb >> 3;                 // 0..271
    int b4   = loc / 68;
    int rem  = loc - b4 * 68;
    int idx  = rem >> 1;                // 0..33 (ascending = heavy first)
    int h32  = rem & 1;                 // which 32-row half of the 64-row block
    int b    = xcd * 4 + b4;
    const int i      = CH_I[idx];
    const int tstart = CH_TS[idx];
    const int tend   = CH_TE[idx];
    const size_t base = (size_t)b * N_;

    // this pair's 16-row tile
    const int  nt   = i * 64 + h32 * 32 + pr * TM;
    const bool wval = (nt < N_);                 // wave-uniform (ragged i=12)
    const int  nrow = wval ? nt : (N_ - TM);     // clamp for loads

    const unsigned short* hb = xhi + base * D_;
    const unsigned short* lb = xlo + base * D_;

    // ---- A fragments: one tile, K-half hf only (64 VGPRs) ----
    const size_t arow = (size_t)(nrow + l16) * D_;
    short8 ah[8], al[8];
    #pragma unroll
    for (int t = 0; t < 8; ++t) {
        int koff = (hf * 8 + t) * 32 + quad * 8;
        ah[t] = *(const short8*)(hb + arow + koff);
        al[t] = *(const short8*)(lb + arow + koff);
    }

    // ---- per-row epilogue constants ----
    float invn[4], sqn[4];
    int   rr[4], rc[4];
    #pragma unroll
    for (int reg = 0; reg < 4; ++reg) {
        int n = nrow + quad * 4 + reg;
        invn[reg] = inv_norm[base + n];
        sqn[reg]  = sqv[base + n];
        rr[reg]   = n / RES_;
        rc[reg]   = n % RES_;
    }

    // ---- stage first tile (tstart): 16 rows x hi/lo, 8 gl_lds16 per wave ----
    #pragma unroll
    for (int j = 0; j < 4; ++j) {
        int r = wv * 4 + j;
        gl_lds16(hb + (size_t)(tstart * TM + r) * D_ + lane * 8, &Bs[0][r * BROW]);
        gl_lds16(lb + (size_t)(tstart * TM + r) * D_ + lane * 8, &Bs[1][r * BROW]);
    }
    __syncthreads();   // drains vmcnt: first tile staged

    for (int t = tstart; t < tend; ++t) {
        // epilogue operands for this tile (issued early)
        int   m    = t * TM + l16;
        float invm = inv_norm[base + m];
        float sqm  = sqv[base + m];
        float relv[4];
        #pragma unroll
        for (int reg = 0; reg < 4; ++reg)
            relv[reg] = rel[(size_t)(nrow + quad * 4 + reg) * N_ + m];

        // 3 independent chains over this wave's K-half
        f32x4 aA = {0.f,0.f,0.f,0.f}, aB = {0.f,0.f,0.f,0.f}, aC = {0.f,0.f,0.f,0.f};
        #pragma unroll
        for (int k = 0; k < 8; ++k) {
            int boff = l16 * BROW + (hf * 8 + k) * 32 + quad * 8;
            short8 bh = *(const short8*)&Bs[0][boff];
            short8 bl = *(const short8*)&Bs[1][boff];
            aA = __builtin_amdgcn_mfma_f32_16x16x32_bf16(al[k], bh, aA, 0, 0, 0);
            aB = __builtin_amdgcn_mfma_f32_16x16x32_bf16(ah[k], bl, aB, 0, 0, 0);
            aC = __builtin_amdgcn_mfma_f32_16x16x32_bf16(ah[k], bh, aC, 0, 0, 0);
        }
        f32x4 part = aA + aB + aC;          // partial dot over K-half hf
        PS[pr][hf][lane] = part;
        __syncthreads();   // PS visible; all waves done reading Bs

        // overwrite Bs with tile t+1 (drained at the bottom barrier)
        if (t + 1 < tend) {
            const size_t rbase = (size_t)(t + 1) * TM;
            #pragma unroll
            for (int j = 0; j < 4; ++j) {
                int r = wv * 4 + j;
                gl_lds16(hb + (rbase + r) * D_ + lane * 8, &Bs[0][r * BROW]);
                gl_lds16(lb + (rbase + r) * D_ + lane * 8, &Bs[1][r * BROW]);
            }
        }

        f32x4 tot = part + PS[pr][hf ^ 1][lane];

        if (wval) {
            int mr = m / RES_, mc = m % RES_;
            float dv[4];
            #pragma unroll
            for (int reg = 0; reg < 4; ++reg) {
                float d = sqn[reg] + sqm - 2.f * invn[reg] * invm * tot[reg] + relv[reg];
                int dr = rr[reg] - mr; if (dr < 0) dr = -dr;
                int dc = rc[reg] - mc; if (dc < 0) dc = -dc;
                if (dr <= 1 && dc <= 1) d += INF_;
                dv[reg] = d;
            }
            if (hf == 0) {
                #pragma unroll
                for (int reg = 0; reg < 4; ++reg) {
                    int n = nrow + quad * 4 + reg;
                    dist[(base + n) * (size_t)N_ + m] = dv[reg];
                }
            } else if (t >= 4 * i + 4) {
                // mirror: dist[m][nrow+quad*4 .. +3] -- one float4 per lane
                float4 q = make_float4(dv[0], dv[1], dv[2], dv[3]);
                *(float4*)(dist + (base + m) * (size_t)N_ + nrow + quad * 4) = q;
            }
        }
        __syncthreads();   // staging drained before next MFMA; PS read done
    }
}

// ---------------------------------------------------------------------------
// Kernel C: one wave per row, XCD-matched to gemm's writer. Lazy top-2 with
// LDS-backed repair (round 12): winner marks its slot with one dynamic
// ds_write; rare full rebuild under a scalar __any guard.
// ---------------------------------------------------------------------------
__global__ __launch_bounds__(256) void topk_direct(
    const float* __restrict__ dist, int* __restrict__ out)
{
    __shared__ float rowS[4][832];          // per-wave row copy + BIGF pad

    const int g    = blockIdx.x;            // 6272 blocks
    const int xcd  = g & 7;
    const int li   = g >> 3;                // 0..783
    const int wv   = threadIdx.x >> 6;
    const int r4   = li * 4 + wv;           // 0..3135 within-XCD row
    const int lane = threadIdx.x & 63;
    const int bl   = r4 / N_;               // 0..3
    const int n    = r4 - bl * N_;
    const int b    = xcd * 4 + bl;
    const int row  = b * N_ + n;
    const size_t base = (size_t)b * N_;

    const float* dr = dist + (size_t)row * N_;
    float* myrow = &rowS[wv][0];

    float vals[13];
    #pragma unroll
    for (int j = 0; j < 3; j++) {
        float4 q = *(const float4*)(dr + j * 256 + lane * 4);
        vals[j * 4 + 0] = q.x; vals[j * 4 + 1] = q.y;
        vals[j * 4 + 2] = q.z; vals[j * 4 + 3] = q.w;
        *(float4*)&myrow[j * 256 + lane * 4] = q;      // LDS mirror
    }
    vals[12] = (lane < 16) ? dr[768 + lane] : BIGF;
    myrow[768 + lane] = vals[12];           // pads [784..832) with BIGF

    // ---- per-lane top-2 (strict <, ascending-mm scan order => stable) ----
    float s1 = BIGF, s2 = BIGF;
    int   i1 = 0x7fffffff, i2 = 0x7fffffff;
    #pragma unroll
    for (int s = 0; s < 13; ++s) {
        int   m = (s < 12) ? ((s >> 2) * 256 + lane * 4 + (s & 3)) : (768 + lane);
        float v = vals[s];
        bool lt1 = v < s1;
        bool lt2 = v < s2;
        float ns2 = lt1 ? s1 : (lt2 ? v : s2);
        int   ni2 = lt1 ? i1 : (lt2 ? m : i2);
        s1 = lt1 ? v : s1;  i1 = lt1 ? m : i1;
        s2 = ns2;           i2 = ni2;
    }

    bool dirty = false, needR = false;
    size_t outbase = (size_t)row * K_ * 3;
    for (int k = 0; k < K_; k++) {
        float cd = s1; int ci = i1;
        #pragma unroll
        for (int off = 32; off >= 1; off >>= 1) {
            float od = __shfl_xor(cd, off, 64);
            int   oi = __shfl_xor(ci, off, 64);
            if (od < cd || (od == cd && oi < ci)) { cd = od; ci = oi; }
        }
        if (lane == 0) {
            out[outbase + (size_t)k * 3 + 0] = (int)base + ci;
            out[outbase + (size_t)k * 3 + 1] = row;
            out[outbase + (size_t)k * 3 + 2] = 0;
        }
        if (ci == i1) {   // unique winner lane (mm sets disjoint across lanes)
            myrow[ci] = BIGF;                // one dynamic LDS mark
            if (!dirty) { s1 = s2; i1 = i2; dirty = true; }
            else        { needR = true; }
        }
        if (__any(needR)) {                  // scalar-guarded rare path
            if (needR) {
                float a1 = BIGF, a2 = BIGF;
                int   b1 = 0x7fffffff, b2 = 0x7fffffff;
                #pragma unroll
                for (int s = 0; s < 13; ++s) {
                    int   m = (s < 12) ? ((s >> 2) * 256 + lane * 4 + (s & 3)) : (768 + lane);
                    float v = myrow[m];
                    bool lt1 = v < a1;
                    bool lt2 = v < a2;
                    float ns2 = lt1 ? a1 : (lt2 ? v : a2);
                    int   ni2 = lt1 ? b1 : (lt2 ? m : b2);
                    a1 = lt1 ? v : a1;  b1 = lt1 ? m : b1;
                    a2 = ns2;           b2 = ni2;
                }
                s1 = a1; i1 = b1; s2 = a2; i2 = b2;
                dirty = false; needR = false;
            }
        }
    }
}

// ===========================================================================
// Fallback (round-4 proven path) — used only if ws can't hold dist scratch.
// ===========================================================================
__global__ __launch_bounds__(256, 2) void dist16_topk(
    const unsigned short* __restrict__ xhi, const unsigned short* __restrict__ xlo,
    const float* __restrict__ rel, const float* __restrict__ inv_norm,
    const float* __restrict__ sqv, int* __restrict__ out)
{
    __shared__ float distS[TM][LDSW];

    const int tid  = threadIdx.x;
    const int wv   = tid >> 6;
    const int lane = tid & 63;
    const int quad = lane >> 4;
    const int l16  = lane & 15;

    int gb   = blockIdx.x;
    int xcd  = gb & 7;
    int loc  = gb >> 3;
    int b    = xcd * 4 + loc / TILES;
    int tile = loc % TILES;
    const int    n0   = tile * TM;
    const size_t base = (size_t)b * N_;

    const unsigned short* hb = xhi + base * D_;
    const unsigned short* lb = xlo + base * D_;

    const size_t arow = (size_t)(n0 + l16) * D_;
    short8 ah[16], al[16];
    #pragma unroll
    for (int t = 0; t < 16; ++t) {
        int koff = t * 32 + quad * 8;
        ah[t] = *(const short8*)(hb + arow + koff);
        al[t] = *(const short8*)(lb + arow + koff);
    }

    float invn[4], sqn[4];
    int   rr[4], rc[4];
    #pragma unroll
    for (int reg = 0; reg < 4; ++reg) {
        int n = n0 + quad * 4 + reg;
        invn[reg] = inv_norm[base + n];
        sqn[reg]  = sqv[base + n];
        rr[reg]   = n / RES_;
        rc[reg]   = n % RES_;
    }

    for (int j0 = 0; j0 < 13; j0 += 2) {
        int  t0 = wv + 4 * j0;
        int  t1 = t0 + 4;
        bool v1 = (t1 < TILES);
        if (t0 >= TILES) break;

        size_t brow0 = (size_t)(t0 * TM + l16) * D_;
        size_t brow1 = v1 ? (size_t)(t1 * TM + l16) * D_ : brow0;

        f32x4 a0a = {0.f,0.f,0.f,0.f}, a0b = {0.f,0.f,0.f,0.f}, a0c = {0.f,0.f,0.f,0.f};
        f32x4 a1a = {0.f,0.f,0.f,0.f}, a1b = {0.f,0.f,0.f,0.f}, a1c = {0.f,0.f,0.f,0.f};

        int k0 = quad * 8;
        short8 c0h = *(const short8*)(hb + brow0 + k0);
        short8 c0l = *(const short8*)(lb + brow0 + k0);
        short8 c1h = *(const short8*)(hb + brow1 + k0);
        short8 c1l = *(const short8*)(lb + brow1 + k0);

        #pragma unroll
        for (int t = 0; t < 16; ++t) {
            short8 n0h, n0l, n1h, n1l;
            if (t < 15) {
                int kn = (t + 1) * 32 + quad * 8;
                n0h = *(const short8*)(hb + brow0 + kn);
                n0l = *(const short8*)(lb + brow0 + kn);
                n1h = *(const short8*)(hb + brow1 + kn);
                n1l = *(const short8*)(lb + brow1 + kn);
            }
            a0a = __builtin_amdgcn_mfma_f32_16x16x32_bf16(al[t], c0h, a0a, 0, 0, 0);
            a1a = __builtin_amdgcn_mfma_f32_16x16x32_bf16(al[t], c1h, a1a, 0, 0, 0);
            a0b = __builtin_amdgcn_mfma_f32_16x16x32_bf16(ah[t], c0l, a0b, 0, 0, 0);
            a1b = __builtin_amdgcn_mfma_f32_16x16x32_bf16(ah[t], c1l, a1b, 0, 0, 0);
            a0c = __builtin_amdgcn_mfma_f32_16x16x32_bf16(ah[t], c0h, a0c, 0, 0, 0);
            a1c = __builtin_amdgcn_mfma_f32_16x16x32_bf16(ah[t], c1h, a1c, 0, 0, 0);
            if (t < 15) { c0h = n0h; c0l = n0l; c1h = n1h; c1l = n1l; }
        }

        #pragma unroll
        for (int p = 0; p < 2; ++p) {
            if (p == 1 && !v1) break;
            int tt = (p == 0) ? t0 : t1;
            f32x4 av;
            if (p == 0) { av = a0a; av += a0b; av += a0c; }
            else        { av = a1a; av += a1b; av += a1c; }
            int m = tt * TM + l16;
            float invm = inv_norm[base + m];
            float sqm  = sqv[base + m];
            int mr = m / RES_, mc = m % RES_;
            #pragma unroll
            for (int reg = 0; reg < 4; ++reg) {
                int n = n0 + quad * 4 + reg;
                float d = sqn[reg] + sqm - 2.f * invn[reg] * invm * av[reg]
                        + rel[(size_t)n * N_ + m];
                int dr = rr[reg] - mr; if (dr < 0) dr = -dr;
                int dc = rc[reg] - mc; if (dc < 0) dc = -dc;
                if (dr <= 1 && dc <= 1) d += INF_;
                distS[quad * 4 + reg][m] = d;
            }
        }
    }
    __syncthreads();

    for (int r = 0; r < 4; ++r) {
        int nl = wv * 4 + r;
        int ng = n0 + nl;
        float vals[13];
        #pragma unroll
        for (int j = 0; j < 13; j++) {
            int mm = lane + 64 * j;
            vals[j] = (mm < N_) ? distS[nl][mm] : BIGF;
        }
        size_t outbase = (size_t)(base + ng) * K_ * 3;
        for (int k = 0; k < K_; k++) {
            float bd = vals[0]; int bi = lane;
            #pragma unroll
            for (int j = 1; j < 13; j++) {
                int mm = lane + 64 * j;
                if (vals[j] < bd || (vals[j] == bd && mm < bi)) { bd = vals[j]; bi = mm; }
            }
            float cd = bd; int ci = bi;
            #pragma unroll
            for (int off = 32; off >= 1; off >>= 1) {
                float od = __shfl_xor(cd, off, 64);
                int   oi = __shfl_xor(ci, off, 64);
                if (od < cd || (od == cd && oi < ci)) { cd = od; ci = oi; }
            }
            #pragma unroll
            for (int j = 0; j < 13; j++) {
                if (ci == lane + 64 * j) vals[j] = BIGF;
            }
            if (lane == 0) {
                out[outbase + (size_t)k * 3 + 0] = (int)base + ci;
                out[outbase + (size_t)k * 3 + 1] = (int)(base + ng);
                out[outbase + (size_t)k * 3 + 2] = 0;
            }
        }
    }
}

extern "C" void kernel_launch(void* const* d_in, const int* in_sizes, int n_in,
                              void* d_out, int out_size, void* d_ws, size_t ws_size,
                              hipStream_t stream) {
    const float* nf  = (const float*)d_in[0];   // [32, 784, 512] f32
    const float* rel = (const float*)d_in[1];   // [1, 784, 784] f32 (already -rel)
    float* inv_norm  = (float*)d_ws;            // [25088]
    float* sq        = inv_norm + B_ * N_;      // [25088]
    int*   out       = (int*)d_out;

    unsigned short* xhi = (unsigned short*)(sq + B_ * N_);
    unsigned short* xlo = xhi + (size_t)B_ * N_ * D_;
    float* dist = (float*)(xlo + (size_t)B_ * N_ * D_);   // [32*784*784]

    size_t need_full = (size_t)2 * B_ * N_ * sizeof(float)
                     + (size_t)2 * B_ * N_ * D_ * sizeof(unsigned short)
                     + (size_t)B_ * N_ * N_ * sizeof(float);

    norm_convert_kernel<<<(B_ * N_) / 4, 256, 0, stream>>>(nf, inv_norm, sq, xhi, xlo);
    if (ws_size >= need_full) {
        gemm32<<<8 * 4 * NCH * 2, 256, 0, stream>>>(xhi, xlo, rel, inv_norm, sq, dist);
        topk_direct<<<(B_ * N_) / 4, 256, 0, stream>>>(dist, out);
    } else {
        dist16_topk<<<8 * 4 * TILES, 256, 0, stream>>>(xhi, xlo, rel, inv_norm, sq, out);
    }
}

// Round 14
// 188.396 us; speedup vs baseline: 1.0918x; 1.0918x over previous
//
#include <hip/hip_runtime.h>
#include <math.h>

#define B_    32
#define N_    784
#define D_    512
#define K_    10
#define RES_  28
#define INF_  100000.0f
#define TM    16
#define TILES (N_ / 16)   // 49
#define BIGF  3.0e38f
#define LDSW  788         // fallback kernel's padded dist row stride
#define BROW  520         // LDS B-tile row stride in shorts (1040 B)
#define NCH   34          // symmetric chunks per batch (<=13 tiles each)

typedef __attribute__((ext_vector_type(8))) short short8;
typedef __attribute__((ext_vector_type(4))) float f32x4;

// chunk tables: row-block i (64 rows), col-tile range [ts, te). Ordered by
// DESCENDING tile count so the HW block queue packs heavy chunks first.
__device__ __constant__ unsigned char CH_I[NCH] =
    {0,0,0,1,1,2,2,3,3,4,5,6, 7, 0,1,2,3,4,4,5,6,7,8,9, 1,10, 8, 5, 2,11, 9, 6, 3,12};
__device__ __constant__ unsigned char CH_TS[NCH] =
    {0,13,26,13,26,13,26,13,26,26,26,26, 28, 39,39,39,39,16,39,39,39,39,39,39, 4,40, 32, 20, 8,44, 36, 24, 12,48};
__device__ __constant__ unsigned char CH_TE[NCH] =
    {13,26,39,26,39,26,39,26,39,39,39,39, 39, 49,49,49,49,26,49,49,49,49,49,49, 13,49, 39, 26, 13,49, 39, 26, 13,49};

__device__ __forceinline__ unsigned short f2bf(float f) {
    unsigned u = __float_as_uint(f);
    unsigned r = (u + 0x7fffu + ((u >> 16) & 1u)) >> 16;   // RNE
    return (unsigned short)r;
}
__device__ __forceinline__ float bf2f(unsigned short h) {
    return __uint_as_float(((unsigned)h) << 16);
}

// async global->LDS, 16 B per lane: LDS dest = uniform base + lane*16.
__device__ __forceinline__ void gl_lds16(const void* g, void* l) {
    __builtin_amdgcn_global_load_lds(
        (const __attribute__((address_space(1))) unsigned int*)g,
        (__attribute__((address_space(3))) unsigned int*)(void*)l, 16, 0, 0);
}

// ---------------------------------------------------------------------------
// Kernel A: per-row inv_norm & sq, plus split-bf16 conversion
// x = hi + lo with hi=bf16(x), lo=bf16(x-hi). One wave per row.
// ---------------------------------------------------------------------------
__global__ __launch_bounds__(256) void norm_convert_kernel(
    const float* __restrict__ nf, float* __restrict__ inv_norm,
    float* __restrict__ sq, unsigned short* __restrict__ xhi,
    unsigned short* __restrict__ xlo)
{
    int wave = threadIdx.x >> 6;
    int lane = threadIdx.x & 63;
    int row  = blockIdx.x * 4 + wave;           // grid exactly covers B_*N_
    const float* rp = nf + (size_t)row * D_;
    float4 a = *(const float4*)(rp + lane * 8);
    float4 b = *(const float4*)(rp + lane * 8 + 4);
    float v[8] = {a.x, a.y, a.z, a.w, b.x, b.y, b.z, b.w};

    float s = 0.f;
    #pragma unroll
    for (int i = 0; i < 8; i++) s = fmaf(v[i], v[i], s);
    #pragma unroll
    for (int off = 32; off >= 1; off >>= 1)
        s += __shfl_xor(s, off, 64);
    if (lane == 0) {
        float nrm = sqrtf(s);
        float iv  = 1.0f / fmaxf(nrm, 1e-12f);
        inv_norm[row] = iv;
        sq[row]       = s * iv * iv;
    }

    unsigned short h[8], l[8];
    #pragma unroll
    for (int i = 0; i < 8; i++) {
        h[i] = f2bf(v[i]);
        float hf = bf2f(h[i]);
        l[i] = f2bf(v[i] - hf);
    }
    size_t off16 = (size_t)row * D_ + lane * 8;
    short8 h8, l8;
    #pragma unroll
    for (int i = 0; i < 8; i++) { h8[i] = (short)h[i]; l8[i] = (short)l[i]; }
    *(short8*)(xhi + off16) = h8;
    *(short8*)(xlo + off16) = l8;
}

// ---------------------------------------------------------------------------
// Kernel B: SYMMETRIC distance GEMM, chunk-scheduled, K-SPLIT, batch-major
// L2 ordering (round 12 — the best measured configuration: ~67 us).
// ---------------------------------------------------------------------------
__global__ __launch_bounds__(256, 2) void gemm64(
    const unsigned short* __restrict__ xhi, const unsigned short* __restrict__ xlo,
    const float* __restrict__ rel, const float* __restrict__ inv_norm,
    const float* __restrict__ sqv, float* __restrict__ dist)
{
    __shared__ unsigned short Bs[2][2][16 * BROW];   // 66560 B
    __shared__ f32x4 PS[2][2][2][64];                // [buf][pair][half][lane] 8 KB

    const int tid  = threadIdx.x;
    const int wv   = tid >> 6;
    const int lane = tid & 63;
    const int quad = lane >> 4;
    const int l16  = lane & 15;
    const int pr   = wv >> 1;           // pair 0..1 (rows)
    const int hf   = wv & 1;            // K-half 0..1

    // 1088 blocks = 8 XCDs * (4 batches * 34 chunks); batch-major so each
    // XCD finishes a batch's chunk list (heavy-first) before the next batch.
    int gb   = blockIdx.x;
    int xcd  = gb & 7;
    int loc  = gb >> 3;                 // 0..135
    int b4   = loc / 34;                // 0..3 (batch within XCD)
    int idx  = loc - b4 * 34;           // 0..33 (ascending = heavy first)
    int b    = xcd * 4 + b4;
    const int i      = CH_I[idx];
    const int tstart = CH_TS[idx];
    const int tend   = CH_TE[idx];
    const int    n0   = i * 64;
    const size_t base = (size_t)b * N_;

    // pair's two row-tiles (clamped separately for the ragged i=12 block)
    const int rt0 = n0 + pr * 32;
    const int rt1 = rt0 + 16;
    const int r0c = (rt0 < N_) ? rt0 : (N_ - TM);
    const int r1c = (rt1 < N_) ? rt1 : (N_ - TM);
    // this wave finalizes tile h of its pair
    const int  nw   = rt0 + hf * TM;
    const bool wval = (nw < N_);                 // wave-uniform
    const int  nrow = wval ? nw : (N_ - TM);

    const unsigned short* hb = xhi + base * D_;
    const unsigned short* lb = xlo + base * D_;

    // ---- A fragments: both row-tiles, K-half hf only (128 VGPRs) ----
    const size_t ar0 = (size_t)(r0c + l16) * D_;
    const size_t ar1 = (size_t)(r1c + l16) * D_;
    short8 ah0[8], al0[8], ah1[8], al1[8];
    #pragma unroll
    for (int t = 0; t < 8; ++t) {
        int koff = (hf * 8 + t) * 32 + quad * 8;
        ah0[t] = *(const short8*)(hb + ar0 + koff);
        al0[t] = *(const short8*)(lb + ar0 + koff);
        ah1[t] = *(const short8*)(hb + ar1 + koff);
        al1[t] = *(const short8*)(lb + ar1 + koff);
    }

    // ---- per-row epilogue constants (for the finalized tile) ----
    float invn[4], sqn[4];
    int   rr[4], rc[4];
    #pragma unroll
    for (int reg = 0; reg < 4; ++reg) {
        int n = nrow + quad * 4 + reg;
        invn[reg] = inv_norm[base + n];
        sqn[reg]  = sqv[base + n];
        rr[reg]   = n / RES_;
        rc[reg]   = n % RES_;
    }

    // ---- stage first tile (tstart) ----
    const int sb0 = tstart & 1;
    #pragma unroll
    for (int j = 0; j < 4; ++j) {
        int r = wv * 4 + j;
        gl_lds16(hb + (size_t)(tstart * TM + r) * D_ + lane * 8, &Bs[sb0][0][r * BROW]);
        gl_lds16(lb + (size_t)(tstart * TM + r) * D_ + lane * 8, &Bs[sb0][1][r * BROW]);
    }
    __syncthreads();   // drains vmcnt: first tile staged

    for (int t = tstart; t < tend; ++t) {
        const int cur = t & 1;
        if (t + 1 < tend) {
            const int nxt = (t + 1) & 1;
            const size_t rbase = (size_t)(t + 1) * TM;
            #pragma unroll
            for (int j = 0; j < 4; ++j) {
                int r = wv * 4 + j;
                gl_lds16(hb + (rbase + r) * D_ + lane * 8, &Bs[nxt][0][r * BROW]);
                gl_lds16(lb + (rbase + r) * D_ + lane * 8, &Bs[nxt][1][r * BROW]);
            }
        }

        // epilogue operands for this tile (issued early)
        int   m    = t * TM + l16;
        float invm = inv_norm[base + m];
        float sqm  = sqv[base + m];
        float relv[4];
        #pragma unroll
        for (int reg = 0; reg < 4; ++reg)
            relv[reg] = rel[(size_t)(nrow + quad * 4 + reg) * N_ + m];

        // 6 independent chains over this wave's K-half
        f32x4 aA0 = {0.f,0.f,0.f,0.f}, aB0 = {0.f,0.f,0.f,0.f}, aC0 = {0.f,0.f,0.f,0.f};
        f32x4 aA1 = {0.f,0.f,0.f,0.f}, aB1 = {0.f,0.f,0.f,0.f}, aC1 = {0.f,0.f,0.f,0.f};
        #pragma unroll
        for (int k = 0; k < 8; ++k) {
            int boff = l16 * BROW + (hf * 8 + k) * 32 + quad * 8;
            short8 bh = *(const short8*)&Bs[cur][0][boff];
            short8 bl = *(const short8*)&Bs[cur][1][boff];
            aA0 = __builtin_amdgcn_mfma_f32_16x16x32_bf16(al0[k], bh, aA0, 0, 0, 0);
            aA1 = __builtin_amdgcn_mfma_f32_16x16x32_bf16(al1[k], bh, aA1, 0, 0, 0);
            aB0 = __builtin_amdgcn_mfma_f32_16x16x32_bf16(ah0[k], bl, aB0, 0, 0, 0);
            aB1 = __builtin_amdgcn_mfma_f32_16x16x32_bf16(ah1[k], bl, aB1, 0, 0, 0);
            aC0 = __builtin_amdgcn_mfma_f32_16x16x32_bf16(ah0[k], bh, aC0, 0, 0, 0);
            aC1 = __builtin_amdgcn_mfma_f32_16x16x32_bf16(ah1[k], bh, aC1, 0, 0, 0);
        }
        f32x4 s0 = aA0 + aB0 + aC0;   // partial dot, rows [rt0, rt0+16)
        f32x4 s1 = aA1 + aB1 + aC1;   // partial dot, rows [rt1, rt1+16)

        // exchange the partial this wave does NOT finalize
        PS[cur][pr][hf][lane] = hf ? s0 : s1;
        __syncthreads();   // PS visible + staged t+1 drained + Bs[cur] free

        f32x4 own  = hf ? s1 : s0;
        f32x4 part = PS[cur][pr][hf ^ 1][lane];
        f32x4 tot  = own + part;

        if (wval) {
            int mr = m / RES_, mc = m % RES_;
            float dv[4];
            #pragma unroll
            for (int reg = 0; reg < 4; ++reg) {
                int n = nrow + quad * 4 + reg;
                float d = sqn[reg] + sqm - 2.f * invn[reg] * invm * tot[reg] + relv[reg];
                int dr = rr[reg] - mr; if (dr < 0) dr = -dr;
                int dc = rc[reg] - mc; if (dc < 0) dc = -dc;
                if (dr <= 1 && dc <= 1) d += INF_;
                dv[reg] = d;
                dist[(base + n) * (size_t)N_ + m] = d;
            }
            if (t >= 4 * i + 4) {
                // mirror: dist[m][nrow+quad*4 .. +3] -- one float4 per lane
                float4 q = make_float4(dv[0], dv[1], dv[2], dv[3]);
                *(float4*)(dist + (base + m) * (size_t)N_ + nrow + quad * 4) = q;
            }
        }
    }
}

// ---------------------------------------------------------------------------
// Kernel C: one wave per row. PAIRED butterfly: each lane carries its sorted
// local top-2 through the 6-step xor-reduction; merging two sorted pairs
// (3 lex compares) yields the EXACT global (min, 2nd-min) per pass -> 5
// passes emit all 10 (serial shuffle chain halved vs 10 single-min passes,
// which rounds 10-12 showed was the stuck cost). Lanes keep a sorted local
// top-4 (static shifts); dropping below 2 live candidates triggers the
// exact LDS-mirror rebuild under a scalar __any guard (~2.6% of rows).
// Selection order identical: lexicographic (value, index).
// ---------------------------------------------------------------------------
__global__ __launch_bounds__(256) void topk_direct(
    const float* __restrict__ dist, int* __restrict__ out)
{
    __shared__ float rowS[4][832];          // per-wave row copy + BIGF pad

    const int g    = blockIdx.x;            // 6272 blocks
    const int xcd  = g & 7;
    const int li   = g >> 3;                // 0..783
    const int wv   = threadIdx.x >> 6;
    const int r4   = li * 4 + wv;           // 0..3135 within-XCD row
    const int lane = threadIdx.x & 63;
    const int bl   = r4 / N_;               // 0..3
    const int n    = r4 - bl * N_;
    const int b    = xcd * 4 + bl;
    const int row  = b * N_ + n;
    const size_t base = (size_t)b * N_;

    const float* dr = dist + (size_t)row * N_;
    float* myrow = &rowS[wv][0];

    float vals[13];
    #pragma unroll
    for (int j = 0; j < 3; j++) {
        float4 q = *(const float4*)(dr + j * 256 + lane * 4);
        vals[j * 4 + 0] = q.x; vals[j * 4 + 1] = q.y;
        vals[j * 4 + 2] = q.z; vals[j * 4 + 3] = q.w;
        *(float4*)&myrow[j * 256 + lane * 4] = q;      // LDS mirror
    }
    vals[12] = (lane < 16) ? dr[768 + lane] : BIGF;
    myrow[768 + lane] = vals[12];           // pads [784..832) with BIGF

    // ---- lane-local sorted top-4 (ascending-mm scan, strict < => lex) ----
    float h1 = BIGF, h2 = BIGF, h3 = BIGF, h4 = BIGF;
    int   e1 = 0x7fffffff, e2 = 0x7fffffff, e3 = 0x7fffffff, e4 = 0x7fffffff;
    #pragma unroll
    for (int s = 0; s < 13; ++s) {
        int   m = (s < 12) ? ((s >> 2) * 256 + lane * 4 + (s & 3)) : (768 + lane);
        float v = vals[s];
        bool c1 = v < h1, c2 = v < h2, c3 = v < h3, c4 = v < h4;
        float nh4 = c4 ? (c3 ? h3 : v) : h4;  int ne4 = c4 ? (c3 ? e3 : m) : e4;
        float nh3 = c3 ? (c2 ? h2 : v) : h3;  int ne3 = c3 ? (c2 ? e2 : m) : e3;
        float nh2 = c2 ? (c1 ? h1 : v) : h2;  int ne2 = c2 ? (c1 ? e1 : m) : e2;
        float nh1 = c1 ? v : h1;              int ne1 = c1 ? m : e1;
        h1 = nh1; h2 = nh2; h3 = nh3; h4 = nh4;
        e1 = ne1; e2 = ne2; e3 = ne3; e4 = ne4;
    }

    size_t outbase = (size_t)row * K_ * 3;
    for (int pass = 0; pass < 5; ++pass) {
        // butterfly over sorted pairs -> exact global (min, 2nd-min)
        float a1 = h1, a2 = h2; int i1 = e1, i2 = e2;
        #pragma unroll
        for (int off = 32; off >= 1; off >>= 1) {
            float b1 = __shfl_xor(a1, off, 64);
            int   j1 = __shfl_xor(i1, off, 64);
            float b2 = __shfl_xor(a2, off, 64);
            int   j2 = __shfl_xor(i2, off, 64);
            bool lt = (b1 < a1) || (b1 == a1 && j1 < i1);
            float m1v = lt ? b1 : a1;  int m1i = lt ? j1 : i1;   // merged min
            float cv  = lt ? a1 : b1;  int cvi = lt ? i1 : j1;   // loser of firsts
            float dv  = lt ? b2 : a2;  int dvi = lt ? j2 : i2;   // winner's second
            bool lt2 = (dv < cv) || (dv == cv && dvi < cvi);
            a1 = m1v; i1 = m1i;
            a2 = lt2 ? dv : cv;  i2 = lt2 ? dvi : cvi;           // merged 2nd
        }
        if (lane == 0) {
            int k = pass * 2;
            out[outbase + (size_t)k * 3 + 0] = (int)base + i1;
            out[outbase + (size_t)k * 3 + 1] = row;
            out[outbase + (size_t)k * 3 + 2] = 0;
            out[outbase + (size_t)(k + 1) * 3 + 0] = (int)base + i2;
            out[outbase + (size_t)(k + 1) * 3 + 1] = row;
            out[outbase + (size_t)(k + 1) * 3 + 2] = 0;
        }
        if (pass == 4) break;

        // consume: g1 can only be an owner's head1; g2 is head1 (other lane)
        // or head2 (same lane as g1). Indices are globally unique.
        bool mine1 = (e1 == i1) || (e1 == i2);
        bool mine2 = (e2 == i2);
        if (mine1) myrow[e1] = BIGF;
        if (mine2) myrow[e2] = BIGF;
        int cnt = (int)mine1 + (int)mine2;
        if (cnt == 1) {
            h1 = h2; e1 = e2; h2 = h3; e2 = e3; h3 = h4; e3 = e4;
            h4 = BIGF; e4 = 0x7fffffff;
        } else if (cnt == 2) {
            h1 = h3; e1 = e3; h2 = h4; e2 = e4;
            h3 = BIGF; e3 = 0x7fffffff; h4 = BIGF; e4 = 0x7fffffff;
        }
        bool needR = (h2 == BIGF);           // <2 live candidates -> rebuild
        if (__any(needR)) {
            if (needR) {
                h1 = BIGF; h2 = BIGF; h3 = BIGF; h4 = BIGF;
                e1 = 0x7fffffff; e2 = 0x7fffffff; e3 = 0x7fffffff; e4 = 0x7fffffff;
                #pragma unroll
                for (int s = 0; s < 13; ++s) {
                    int   m = (s < 12) ? ((s >> 2) * 256 + lane * 4 + (s & 3)) : (768 + lane);
                    float v = myrow[m];
                    bool c1 = v < h1, c2 = v < h2, c3 = v < h3, c4 = v < h4;
                    float nh4 = c4 ? (c3 ? h3 : v) : h4;  int ne4 = c4 ? (c3 ? e3 : m) : e4;
                    float nh3 = c3 ? (c2 ? h2 : v) : h3;  int ne3 = c3 ? (c2 ? e2 : m) : e3;
                    float nh2 = c2 ? (c1 ? h1 : v) : h2;  int ne2 = c2 ? (c1 ? e1 : m) : e2;
                    float nh1 = c1 ? v : h1;              int ne1 = c1 ? m : e1;
                    h1 = nh1; h2 = nh2; h3 = nh3; h4 = nh4;
                    e1 = ne1; e2 = ne2; e3 = ne3; e4 = ne4;
                }
            }
        }
    }
}

// ===========================================================================
// Fallback (round-4 proven path) — used only if ws can't hold dist scratch.
// ===========================================================================
__global__ __launch_bounds__(256, 2) void dist16_topk(
    const unsigned short* __restrict__ xhi, const unsigned short* __restrict__ xlo,
    const float* __restrict__ rel, const float* __restrict__ inv_norm,
    const float* __restrict__ sqv, int* __restrict__ out)
{
    __shared__ float distS[TM][LDSW];

    const int tid  = threadIdx.x;
    const int wv   = tid >> 6;
    const int lane = tid & 63;
    const int quad = lane >> 4;
    const int l16  = lane & 15;

    int gb   = blockIdx.x;
    int xcd  = gb & 7;
    int loc  = gb >> 3;
    int b    = xcd * 4 + loc / TILES;
    int tile = loc % TILES;
    const int    n0   = tile * TM;
    const size_t base = (size_t)b * N_;

    const unsigned short* hb = xhi + base * D_;
    const unsigned short* lb = xlo + base * D_;

    const size_t arow = (size_t)(n0 + l16) * D_;
    short8 ah[16], al[16];
    #pragma unroll
    for (int t = 0; t < 16; ++t) {
        int koff = t * 32 + quad * 8;
        ah[t] = *(const short8*)(hb + arow + koff);
        al[t] = *(const short8*)(lb + arow + koff);
    }

    float invn[4], sqn[4];
    int   rr[4], rc[4];
    #pragma unroll
    for (int reg = 0; reg < 4; ++reg) {
        int n = n0 + quad * 4 + reg;
        invn[reg] = inv_norm[base + n];
        sqn[reg]  = sqv[base + n];
        rr[reg]   = n / RES_;
        rc[reg]   = n % RES_;
    }

    for (int j0 = 0; j0 < 13; j0 += 2) {
        int  t0 = wv + 4 * j0;
        int  t1 = t0 + 4;
        bool v1 = (t1 < TILES);
        if (t0 >= TILES) break;

        size_t brow0 = (size_t)(t0 * TM + l16) * D_;
        size_t brow1 = v1 ? (size_t)(t1 * TM + l16) * D_ : brow0;

        f32x4 a0a = {0.f,0.f,0.f,0.f}, a0b = {0.f,0.f,0.f,0.f}, a0c = {0.f,0.f,0.f,0.f};
        f32x4 a1a = {0.f,0.f,0.f,0.f}, a1b = {0.f,0.f,0.f,0.f}, a1c = {0.f,0.f,0.f,0.f};

        int k0 = quad * 8;
        short8 c0h = *(const short8*)(hb + brow0 + k0);
        short8 c0l = *(const short8*)(lb + brow0 + k0);
        short8 c1h = *(const short8*)(hb + brow1 + k0);
        short8 c1l = *(const short8*)(lb + brow1 + k0);

        #pragma unroll
        for (int t = 0; t < 16; ++t) {
            short8 n0h, n0l, n1h, n1l;
            if (t < 15) {
                int kn = (t + 1) * 32 + quad * 8;
                n0h = *(const short8*)(hb + brow0 + kn);
                n0l = *(const short8*)(lb + brow0 + kn);
                n1h = *(const short8*)(hb + brow1 + kn);
                n1l = *(const short8*)(lb + brow1 + kn);
            }
            a0a = __builtin_amdgcn_mfma_f32_16x16x32_bf16(al[t], c0h, a0a, 0, 0, 0);
            a1a = __builtin_amdgcn_mfma_f32_16x16x32_bf16(al[t], c1h, a1a, 0, 0, 0);
            a0b = __builtin_amdgcn_mfma_f32_16x16x32_bf16(ah[t], c0l, a0b, 0, 0, 0);
            a1b = __builtin_amdgcn_mfma_f32_16x16x32_bf16(ah[t], c1l, a1b, 0, 0, 0);
            a0c = __builtin_amdgcn_mfma_f32_16x16x32_bf16(ah[t], c0h, a0c, 0, 0, 0);
            a1c = __builtin_amdgcn_mfma_f32_16x16x32_bf16(ah[t], c1h, a1c, 0, 0, 0);
            if (t < 15) { c0h = n0h; c0l = n0l; c1h = n1h; c1l = n1l; }
        }

        #pragma unroll
        for (int p = 0; p < 2; ++p) {
            if (p == 1 && !v1) break;
            int tt = (p == 0) ? t0 : t1;
            f32x4 av;
            if (p == 0) { av = a0a; av += a0b; av += a0c; }
            else        { av = a1a; av += a1b; av += a1c; }
            int m = tt * TM + l16;
            float invm = inv_norm[base + m];
            float sqm  = sqv[base + m];
            int mr = m / RES_, mc = m % RES_;
            #pragma unroll
            for (int reg = 0; reg < 4; ++reg) {
                int n = n0 + quad * 4 + reg;
                float d = sqn[reg] + sqm - 2.f * invn[reg] * invm * av[reg]
                        + rel[(size_t)n * N_ + m];
                int dr = rr[reg] - mr; if (dr < 0) dr = -dr;
                int dc = rc[reg] - mc; if (dc < 0) dc = -dc;
                if (dr <= 1 && dc <= 1) d += INF_;
                distS[quad * 4 + reg][m] = d;
            }
        }
    }
    __syncthreads();

    for (int r = 0; r < 4; ++r) {
        int nl = wv * 4 + r;
        int ng = n0 + nl;
        float vals[13];
        #pragma unroll
        for (int j = 0; j < 13; j++) {
            int mm = lane + 64 * j;
            vals[j] = (mm < N_) ? distS[nl][mm] : BIGF;
        }
        size_t outbase = (size_t)(base + ng) * K_ * 3;
        for (int k = 0; k < K_; k++) {
            float bd = vals[0]; int bi = lane;
            #pragma unroll
            for (int j = 1; j < 13; j++) {
                int mm = lane + 64 * j;
                if (vals[j] < bd || (vals[j] == bd && mm < bi)) { bd = vals[j]; bi = mm; }
            }
            float cd = bd; int ci = bi;
            #pragma unroll
            for (int off = 32; off >= 1; off >>= 1) {
                float od = __shfl_xor(cd, off, 64);
                int   oi = __shfl_xor(ci, off, 64);
                if (od < cd || (od == cd && oi < ci)) { cd = od; ci = oi; }
            }
            #pragma unroll
            for (int j = 0; j < 13; j++) {
                if (ci == lane + 64 * j) vals[j] = BIGF;
            }
            if (lane == 0) {
                out[outbase + (size_t)k * 3 + 0] = (int)base + ci;
                out[outbase + (size_t)k * 3 + 1] = (int)(base + ng);
                out[outbase + (size_t)k * 3 + 2] = 0;
            }
        }
    }
}

extern "C" void kernel_launch(void* const* d_in, const int* in_sizes, int n_in,
                              void* d_out, int out_size, void* d_ws, size_t ws_size,
                              hipStream_t stream) {
    const float* nf  = (const float*)d_in[0];   // [32, 784, 512] f32
    const float* rel = (const float*)d_in[1];   // [1, 784, 784] f32 (already -rel)
    float* inv_norm  = (float*)d_ws;            // [25088]
    float* sq        = inv_norm + B_ * N_;      // [25088]
    int*   out       = (int*)d_out;

    unsigned short* xhi = (unsigned short*)(sq + B_ * N_);
    unsigned short* xlo = xhi + (size_t)B_ * N_ * D_;
    float* dist = (float*)(xlo + (size_t)B_ * N_ * D_);   // [32*784*784]

    size_t need_full = (size_t)2 * B_ * N_ * sizeof(float)
                     + (size_t)2 * B_ * N_ * D_ * sizeof(unsigned short)
                     + (size_t)B_ * N_ * N_ * sizeof(float);

    norm_convert_kernel<<<(B_ * N_) / 4, 256, 0, stream>>>(nf, inv_norm, sq, xhi, xlo);
    if (ws_size >= need_full) {
        gemm64<<<8 * 4 * NCH, 256, 0, stream>>>(xhi, xlo, rel, inv_norm, sq, dist);
        topk_direct<<<(B_ * N_) / 4, 256, 0, stream>>>(dist, out);
    } else {
        dist16_topk<<<8 * 4 * TILES, 256, 0, stream>>>(xhi, xlo, rel, inv_norm, sq, out);
    }
}